// Round 1
// baseline (123.356 us; speedup 1.0000x reference)
//
#include <hip/hip_runtime.h>
#include <hip/hip_bf16.h>

#define B_DIM 16
#define T_DIM 128
#define R_DIM 2048
#define ABITS 20
#define VBITS 32

// ---------------------------------------------------------------------------
// Kernel 1: parallel hash-map build per batch.
// Semantics of the sequential scan reduce to:
//   - an entry exists for address a iff t is the FIRST occurrence of a
//   - its value is the LAST value written to a
//   - entries are ordered by first-occurrence t; count = #distinct addresses
// One block per batch, T=128 threads (thread t owns write t).
// ---------------------------------------------------------------------------
__global__ __launch_bounds__(T_DIM) void build_kernel(
    const float* __restrict__ waddr,   // [B,T,20]
    const float* __restrict__ wval,    // [B,T,32]
    int* __restrict__ keys,            // [B,128]
    unsigned* __restrict__ vals,       // [B,128]
    int* __restrict__ count)           // [B]
{
    const int b = blockIdx.x;
    const int t = threadIdx.x;

    __shared__ unsigned s_addr[T_DIM];
    __shared__ unsigned s_val[T_DIM];
    __shared__ unsigned s_first[T_DIM];

    // Decode +/-1 float encodings back to integers (enc is exactly +-1.0f).
    const float* ap = waddr + (size_t)(b * T_DIM + t) * ABITS;
    unsigned a = 0;
    #pragma unroll
    for (int i = 0; i < ABITS; ++i) a |= (ap[i] > 0.f ? 1u : 0u) << i;

    const float* vp = wval + (size_t)(b * T_DIM + t) * VBITS;
    unsigned v = 0;
    #pragma unroll
    for (int i = 0; i < VBITS; ++i) v |= (vp[i] > 0.f ? 1u : 0u) << i;

    s_addr[t] = a;
    s_val[t]  = v;
    __syncthreads();

    // First-occurrence flag: no earlier t' with the same address.
    unsigned first = 1;
    for (int u = 0; u < t; ++u)
        if (s_addr[u] == a) { first = 0; break; }
    s_first[t] = first;
    __syncthreads();

    // Exclusive prefix sum of first-flags -> slot index (T=128, naive is fine).
    int idx = 0;
    for (int u = 0; u < t; ++u) idx += (int)s_first[u];

    if (first) {
        // Last write wins for the value.
        unsigned val = v;
        for (int u = t + 1; u < T_DIM; ++u)
            if (s_addr[u] == a) val = s_val[u];
        keys[b * T_DIM + idx] = (int)a;
        vals[b * T_DIM + idx] = val;
    }
    if (t == T_DIM - 1) count[b] = idx + (int)first;
}

// ---------------------------------------------------------------------------
// Kernel 2: attention read.
// score_e = (20 - 2*popcount(key_e ^ a)) * TEMP; softmax over valid entries
// -> w_e = exp(-20 * (d_e - d_min));  out_j = sum w_e * (+-1)_{e,j} / sum w_e.
// Invalid (e >= count) entries have weight exactly 0 (matches exp(-1e9-M)=0).
// One thread per read; 8 blocks of 256 per batch; keys/vals staged in LDS.
// ---------------------------------------------------------------------------
__global__ __launch_bounds__(256) void read_kernel(
    const float* __restrict__ raddr,   // [B,R,20]
    const int* __restrict__ keys,      // [B,128]
    const unsigned* __restrict__ vals, // [B,128]
    const int* __restrict__ count,     // [B]
    float* __restrict__ out)           // [B,R,32]
{
    const int b = blockIdx.x >> 3;                       // 8 blocks per batch
    const int r = ((blockIdx.x & 7) << 8) + threadIdx.x; // 0..2047

    __shared__ unsigned s_keys[T_DIM];
    __shared__ unsigned s_vals[T_DIM];
    __shared__ int s_cnt;

    if (threadIdx.x == 0) s_cnt = count[b];
    if (threadIdx.x < T_DIM) {
        s_keys[threadIdx.x] = (unsigned)keys[b * T_DIM + threadIdx.x];
        s_vals[threadIdx.x] = vals[b * T_DIM + threadIdx.x];
    }
    __syncthreads();
    const int cnt = s_cnt;

    // Decode read address.
    const float* ap = raddr + (size_t)(b * R_DIM + r) * ABITS;
    unsigned a = 0;
    #pragma unroll
    for (int i = 0; i < ABITS; ++i) a |= (ap[i] > 0.f ? 1u : 0u) << i;

    // Pass 1: min Hamming distance (softmax max).
    int dmin = 33;
    for (int e = 0; e < cnt; ++e) {
        int d = __popc(s_keys[e] ^ a);
        dmin = min(dmin, d);
    }

    // Pass 2: weights + accumulate.
    float W = 0.f;
    float acc[VBITS];
    #pragma unroll
    for (int j = 0; j < VBITS; ++j) acc[j] = 0.f;

    for (int e = 0; e < cnt; ++e) {
        int d = __popc(s_keys[e] ^ a);
        float w = __expf(-20.0f * (float)(d - dmin));
        W += w;
        unsigned vb = s_vals[e];
        #pragma unroll
        for (int j = 0; j < VBITS; ++j)
            acc[j] += ((vb >> j) & 1u) ? w : -w;
    }

    const float inv = 1.0f / W;
    float* op = out + ((size_t)(b * R_DIM + r) * VBITS);
    #pragma unroll
    for (int j = 0; j < VBITS; ++j) op[j] = acc[j] * inv;
}

extern "C" void kernel_launch(void* const* d_in, const int* in_sizes, int n_in,
                              void* d_out, int out_size, void* d_ws, size_t ws_size,
                              hipStream_t stream) {
    const float* waddr = (const float*)d_in[0]; // [16,128,20]
    const float* wval  = (const float*)d_in[1]; // [16,128,32]
    const float* raddr = (const float*)d_in[2]; // [16,2048,20]
    float* out = (float*)d_out;                 // [16,2048,32]

    // Workspace layout (d_ws is re-poisoned each call; we fully overwrite).
    int*      keys = (int*)d_ws;                        // 16*128*4 = 8192 B
    unsigned* vals = (unsigned*)((char*)d_ws + 8192);   // 8192 B
    int*      cnt  = (int*)((char*)d_ws + 16384);       // 64 B

    build_kernel<<<B_DIM, T_DIM, 0, stream>>>(waddr, wval, keys, vals, cnt);
    read_kernel<<<B_DIM * (R_DIM / 256), 256, 0, stream>>>(raddr, keys, vals, cnt, out);
}

// Round 2
// 87.294 us; speedup vs baseline: 1.4131x; 1.4131x over previous
//
#include <hip/hip_runtime.h>
#include <hip/hip_bf16.h>

#define B_DIM 16
#define T_DIM 128
#define R_DIM 2048
#define ABITS 20
#define VBITS 32
#define SPLIT 8                    // threads cooperating on one read
#define RPB   32                   // reads per 256-thread block

// ---------------------------------------------------------------------------
// Kernel 1: parallel hash-map build per batch (branch-free, pipelined).
//   entry exists iff t is FIRST occurrence of address; value = LAST write;
//   slot = #distinct addresses before t; count = #distinct addresses.
// All loops are fixed-trip independent LDS reads -> compiler can pipeline.
// ---------------------------------------------------------------------------
__global__ __launch_bounds__(T_DIM) void build_kernel(
    const float* __restrict__ waddr,   // [B,T,20]
    const float* __restrict__ wval,    // [B,T,32]
    unsigned* __restrict__ keys,       // [B,128]
    unsigned* __restrict__ vals,       // [B,128]
    int* __restrict__ count)           // [B]
{
    const int b = blockIdx.x;
    const int t = threadIdx.x;

    __shared__ unsigned s_addr[T_DIM];
    __shared__ unsigned s_val[T_DIM];
    __shared__ unsigned s_first[T_DIM];

    // Decode +/-1 float encodings to packed ints (vectorized float4 loads).
    const float4* ap = (const float4*)(waddr + (size_t)(b * T_DIM + t) * ABITS);
    unsigned a = 0;
    #pragma unroll
    for (int q = 0; q < ABITS / 4; ++q) {
        float4 f = ap[q];
        a |= (unsigned)(f.x > 0.f) << (4 * q + 0);
        a |= (unsigned)(f.y > 0.f) << (4 * q + 1);
        a |= (unsigned)(f.z > 0.f) << (4 * q + 2);
        a |= (unsigned)(f.w > 0.f) << (4 * q + 3);
    }
    const float4* vp = (const float4*)(wval + (size_t)(b * T_DIM + t) * VBITS);
    unsigned v = 0;
    #pragma unroll
    for (int q = 0; q < VBITS / 4; ++q) {
        float4 f = vp[q];
        v |= (unsigned)(f.x > 0.f) << (4 * q + 0);
        v |= (unsigned)(f.y > 0.f) << (4 * q + 1);
        v |= (unsigned)(f.z > 0.f) << (4 * q + 2);
        v |= (unsigned)(f.w > 0.f) << (4 * q + 3);
    }

    s_addr[t] = a;
    s_val[t]  = v;
    __syncthreads();

    // First-occurrence: any earlier t' with same address? (independent reads)
    const uint4* sa4 = (const uint4*)s_addr;
    unsigned conflict = 0;
    #pragma unroll 8
    for (int u4 = 0; u4 < T_DIM / 4; ++u4) {
        uint4 kk = sa4[u4];
        int u = u4 * 4;
        conflict |= (unsigned)((kk.x == a) & (u + 0 < t));
        conflict |= (unsigned)((kk.y == a) & (u + 1 < t));
        conflict |= (unsigned)((kk.z == a) & (u + 2 < t));
        conflict |= (unsigned)((kk.w == a) & (u + 3 < t));
    }
    const unsigned first = conflict ^ 1u;
    s_first[t] = first;
    __syncthreads();

    // Combined pass: exclusive prefix of first-flags (slot) + last-value scan.
    int idx = 0;
    unsigned val = v;
    #pragma unroll 4
    for (int u = 0; u < T_DIM; ++u) {
        idx += (int)(s_first[u] & (unsigned)(u < t));
        val = ((s_addr[u] == a) & (u > t)) ? s_val[u] : val;  // ascending: last wins
    }

    if (first) {
        keys[b * T_DIM + idx] = a;
        vals[b * T_DIM + idx] = val;
    }
    if (t == T_DIM - 1) count[b] = idx + (int)first;
}

// ---------------------------------------------------------------------------
// Kernel 2: attention read, exp-free.
// weights = softmax(20*(20-2d)) == exp(-20*(d-dmin)); the d>dmin tail is
// <= 128*e^-20 ~ 2.6e-7 relative -> drop it. out_j = (2*ones_j - n)/n over
// the n entries at minimal Hamming distance.
// 8 threads per read (4 output bits each, byte-packed counters). 256K threads
// = 4 waves/SIMD. Entries via broadcast ds_read_b128 from LDS.
// ---------------------------------------------------------------------------
__global__ __launch_bounds__(256) void read_kernel(
    const float* __restrict__ raddr,     // [B,R,20]
    const unsigned* __restrict__ keys,   // [B,128]
    const unsigned* __restrict__ vals,   // [B,128]
    const int* __restrict__ count,       // [B]
    float* __restrict__ out)             // [B,R,32]
{
    const int blocks_per_b = R_DIM / RPB;            // 64
    const int b    = blockIdx.x / blocks_per_b;
    const int rblk = blockIdx.x % blocks_per_b;
    const int t  = threadIdx.x;
    const int rl = t >> 3;        // 0..31 local read
    const int k  = t & 7;         // 0..7 bit-group (bits 4k..4k+3)

    __shared__ unsigned s_keys[T_DIM];
    __shared__ unsigned s_vals[T_DIM];
    __shared__ float    s_f[RPB * ABITS];   // 640 floats of read-addr encoding
    __shared__ int      s_cnt;

    // Stage table (coalesced per wave) + this block's read addresses.
    if (t < T_DIM)            s_keys[t]          = keys[b * T_DIM + t];
    else if (t < 2 * T_DIM)   s_vals[t - T_DIM]  = vals[b * T_DIM + (t - T_DIM)];
    if (t == 0) s_cnt = count[b];

    const float4* rp = (const float4*)(raddr + ((size_t)b * R_DIM + (size_t)rblk * RPB) * ABITS);
    if (t < RPB * ABITS / 4) ((float4*)s_f)[t] = rp[t];   // 160 float4, coalesced
    __syncthreads();

    // Decode my read address from LDS (banks conflict-free: rl*20 mod 32 distinct).
    const float* f = s_f + rl * ABITS;
    unsigned a = 0;
    #pragma unroll
    for (int i = 0; i < ABITS; ++i) a |= (unsigned)(f[i] > 0.f) << i;

    const int cnt = s_cnt;

    // Pass 1: min Hamming distance over valid entries (invalid forced to >=64).
    const uint4* k4 = (const uint4*)s_keys;
    int dmin = 64;
    #pragma unroll 4
    for (int e4 = 0; e4 < T_DIM / 4; ++e4) {
        uint4 kk = k4[e4];
        int e = e4 * 4;
        int d0 = __popc(kk.x ^ a) | ((e + 0 >= cnt) ? 64 : 0);
        int d1 = __popc(kk.y ^ a) | ((e + 1 >= cnt) ? 64 : 0);
        int d2 = __popc(kk.z ^ a) | ((e + 2 >= cnt) ? 64 : 0);
        int d3 = __popc(kk.w ^ a) | ((e + 3 >= cnt) ? 64 : 0);
        dmin = min(dmin, min(min(d0, d1), min(d2, d3)));
    }

    // Pass 2: count matches (n) and per-bit ones, byte-packed 4 counters/reg.
    const uint4* v4 = (const uint4*)s_vals;
    const unsigned sh = (unsigned)(k * 4);
    unsigned n = 0, ones = 0;
    #pragma unroll 4
    for (int e4 = 0; e4 < T_DIM / 4; ++e4) {
        uint4 kk = k4[e4];
        uint4 vv = v4[e4];
        int e = e4 * 4;
        {
            unsigned m = (unsigned)((__popc(kk.x ^ a) | ((e + 0 >= cnt) ? 64 : 0)) == dmin);
            n += m;
            unsigned bits = (vv.x >> sh) & 0xFu;
            ones += ((bits * 0x00204081u) & 0x01010101u) & (0u - m);
        }
        {
            unsigned m = (unsigned)((__popc(kk.y ^ a) | ((e + 1 >= cnt) ? 64 : 0)) == dmin);
            n += m;
            unsigned bits = (vv.y >> sh) & 0xFu;
            ones += ((bits * 0x00204081u) & 0x01010101u) & (0u - m);
        }
        {
            unsigned m = (unsigned)((__popc(kk.z ^ a) | ((e + 2 >= cnt) ? 64 : 0)) == dmin);
            n += m;
            unsigned bits = (vv.z >> sh) & 0xFu;
            ones += ((bits * 0x00204081u) & 0x01010101u) & (0u - m);
        }
        {
            unsigned m = (unsigned)((__popc(kk.w ^ a) | ((e + 3 >= cnt) ? 64 : 0)) == dmin);
            n += m;
            unsigned bits = (vv.w >> sh) & 0xFu;
            ones += ((bits * 0x00204081u) & 0x01010101u) & (0u - m);
        }
    }

    // out_j = (2*ones_j - n) / n for my 4 bits; coalesced float4 store.
    const float fn  = (float)n;
    const float inv = 1.0f / fn;
    float4 o;
    o.x = (2.0f * (float)((ones      ) & 0xFFu) - fn) * inv;
    o.y = (2.0f * (float)((ones >>  8) & 0xFFu) - fn) * inv;
    o.z = (2.0f * (float)((ones >> 16) & 0xFFu) - fn) * inv;
    o.w = (2.0f * (float)((ones >> 24) & 0xFFu) - fn) * inv;
    float4* op = (float4*)(out + (((size_t)b * R_DIM + (size_t)rblk * RPB + rl) * VBITS + k * 4));
    *op = o;
}

extern "C" void kernel_launch(void* const* d_in, const int* in_sizes, int n_in,
                              void* d_out, int out_size, void* d_ws, size_t ws_size,
                              hipStream_t stream) {
    const float* waddr = (const float*)d_in[0]; // [16,128,20]
    const float* wval  = (const float*)d_in[1]; // [16,128,32]
    const float* raddr = (const float*)d_in[2]; // [16,2048,20]
    float* out = (float*)d_out;                 // [16,2048,32]

    unsigned* keys = (unsigned*)d_ws;                      // 8192 B
    unsigned* vals = (unsigned*)((char*)d_ws + 8192);      // 8192 B
    int*      cnt  = (int*)((char*)d_ws + 16384);          // 64 B

    build_kernel<<<B_DIM, T_DIM, 0, stream>>>(waddr, wval, keys, vals, cnt);
    read_kernel<<<B_DIM * (R_DIM / RPB), 256, 0, stream>>>(raddr, keys, vals, cnt, out);
}

// Round 3
// 69.139 us; speedup vs baseline: 1.7842x; 1.2626x over previous
//
#include <hip/hip_runtime.h>
#include <hip/hip_bf16.h>

#define B_DIM 16
#define T_DIM 128
#define R_DIM 2048
#define ABITS 20
#define VBITS 32
#define RPB   32                       // reads per block
#define BLOCKS_PER_B (R_DIM / RPB)     // 64

// ---------------------------------------------------------------------------
// Fused build+read. One block handles RPB=32 reads of one batch and
// (redundantly, per block) rebuilds that batch's hash table in LDS.
//
// Build (order-invariant under softmax -> slots assigned by LDS atomicAdd):
//   entry exists iff write t is FIRST occurrence of its address,
//   value = LAST write to that address, n = #distinct addresses.
//   One O(128) scan per write computes {any-earlier-equal, any-later-equal,
//   first-equal-index t0} simultaneously.
//
// Read (exp-free: softmax tail e^-20 ~ 2e-9 dropped; out = mean of +-1 bits
// over min-Hamming-distance entries):
//   8 threads per read; thread k owns entries [16k,16k+16) AND output bits
//   [4k,4k+4). Local dmin -> shfl_xor min merge; local 16-bit match mask ->
//   shfl-assembled 128-bit mask m[4]; ones_j = popc(m & valT_j) against a
//   bit-transposed value table built once per block.
// ---------------------------------------------------------------------------
__global__ __launch_bounds__(256) void fused_kernel(
    const float* __restrict__ waddr,   // [B,T,20]
    const float* __restrict__ wval,    // [B,T,32]
    const float* __restrict__ raddr,   // [B,R,20]
    float* __restrict__ out)           // [B,R,32]
{
    const int b    = blockIdx.x / BLOCKS_PER_B;
    const int rblk = blockIdx.x % BLOCKS_PER_B;
    const int t    = threadIdx.x;

    __shared__ unsigned s_addr[T_DIM];      // write addrs, by write index
    __shared__ unsigned s_val[T_DIM];       // write vals, by write index
    __shared__ unsigned s_key[T_DIM];       // keys, by slot
    __shared__ unsigned s_vbits[T_DIM];     // values, by slot
    __shared__ int      s_slotmap[T_DIM];   // first-occurrence t -> slot
    __shared__ float    s_f[RPB * ABITS];   // this block's read-addr encodings
    __shared__ unsigned s_valT[VBITS * 4];  // valT[j][w]: bit j across entries
    __shared__ int      s_n;

    if (t == 0) s_n = 0;

    // Stage read addresses (160 float4, coalesced).
    const float4* rp = (const float4*)(raddr + ((size_t)b * R_DIM + (size_t)rblk * RPB) * ABITS);
    if (t < RPB * ABITS / 4) ((float4*)s_f)[t] = rp[t];

    // Decode write addresses (threads 0-127) and write values (threads 128-255).
    if (t < T_DIM) {
        const float4* ap = (const float4*)(waddr + (size_t)(b * T_DIM + t) * ABITS);
        unsigned a = 0;
        #pragma unroll
        for (int q = 0; q < ABITS / 4; ++q) {
            float4 f = ap[q];
            a |= (unsigned)(f.x > 0.f) << (4 * q + 0);
            a |= (unsigned)(f.y > 0.f) << (4 * q + 1);
            a |= (unsigned)(f.z > 0.f) << (4 * q + 2);
            a |= (unsigned)(f.w > 0.f) << (4 * q + 3);
        }
        s_addr[t] = a;
    } else {
        const int tv = t - T_DIM;
        const float4* vp = (const float4*)(wval + (size_t)(b * T_DIM + tv) * VBITS);
        unsigned v = 0;
        #pragma unroll
        for (int q = 0; q < VBITS / 4; ++q) {
            float4 f = vp[q];
            v |= (unsigned)(f.x > 0.f) << (4 * q + 0);
            v |= (unsigned)(f.y > 0.f) << (4 * q + 1);
            v |= (unsigned)(f.z > 0.f) << (4 * q + 2);
            v |= (unsigned)(f.w > 0.f) << (4 * q + 3);
        }
        s_val[tv] = v;
    }
    __syncthreads();

    // Dedup scan: first/last/first-index in one pass (threads < 128).
    int lastc = 0, t0 = t;
    if (t < T_DIM) {
        const unsigned a = s_addr[t];
        int firstc = 0;
        const uint4* a4 = (const uint4*)s_addr;
        #pragma unroll 8
        for (int u4 = 0; u4 < T_DIM / 4; ++u4) {
            uint4 kk = a4[u4];
            int u = u4 * 4;
            int e0 = (kk.x == a), e1 = (kk.y == a), e2 = (kk.z == a), e3 = (kk.w == a);
            firstc |= (e0 & (u + 0 < t)) | (e1 & (u + 1 < t)) | (e2 & (u + 2 < t)) | (e3 & (u + 3 < t));
            lastc  |= (e0 & (u + 0 > t)) | (e1 & (u + 1 > t)) | (e2 & (u + 2 > t)) | (e3 & (u + 3 > t));
            t0 = (e0 && (u + 0 < t0)) ? (u + 0) : t0;
            t0 = (e1 && (u + 1 < t0)) ? (u + 1) : t0;
            t0 = (e2 && (u + 2 < t0)) ? (u + 2) : t0;
            t0 = (e3 && (u + 3 < t0)) ? (u + 3) : t0;
        }
        if (!firstc) {                       // I am the first occurrence
            int slot = atomicAdd(&s_n, 1);   // order-free slot assignment
            s_key[slot] = a;
            s_slotmap[t] = slot;
        }
    }
    __syncthreads();
    const int n = s_n;
    if (t < T_DIM && !lastc)                 // I am the last write to this addr
        s_vbits[s_slotmap[t0]] = s_val[t];
    __syncthreads();

    // Bit-transpose values: valT[j][w] = bit j of entries [32w,32w+32).
    // (slots >= n hold garbage; they never match dmin — masked below.)
    if (t < 128) {
        const int j = t & 31, w = t >> 5;
        unsigned word = 0;
        #pragma unroll 8
        for (int i = 0; i < 32; ++i)
            word |= ((s_vbits[w * 32 + i] >> j) & 1u) << i;
        s_valT[j * 4 + w] = word;
    }

    // Decode my read address (broadcast-friendly LDS reads).
    const int rl = t >> 3;     // local read 0..31
    const int k  = t & 7;      // my entry-group / output-bit-group
    const float* f = s_f + rl * ABITS;
    unsigned ra = 0;
    #pragma unroll
    for (int i = 0; i < ABITS; ++i) ra |= (unsigned)(f[i] > 0.f) << i;

    // Pass 1: local min Hamming distance over my 16 entries (invalid -> >=64).
    const uint4* k4 = (const uint4*)s_key;
    int dmin = 127;
    #pragma unroll
    for (int j = 0; j < 4; ++j) {
        uint4 kk = k4[k * 4 + j];
        int e = k * 16 + j * 4;
        int d0 = __popc(kk.x ^ ra) | ((e + 0 >= n) ? 64 : 0);
        int d1 = __popc(kk.y ^ ra) | ((e + 1 >= n) ? 64 : 0);
        int d2 = __popc(kk.z ^ ra) | ((e + 2 >= n) ? 64 : 0);
        int d3 = __popc(kk.w ^ ra) | ((e + 3 >= n) ? 64 : 0);
        dmin = min(dmin, min(min(d0, d1), min(d2, d3)));
    }
    // Merge dmin across the 8 lanes of this read (same wave, aligned group).
    dmin = min(dmin, __shfl_xor(dmin, 1, 8));
    dmin = min(dmin, __shfl_xor(dmin, 2, 8));
    dmin = min(dmin, __shfl_xor(dmin, 4, 8));

    // Pass 2: local 16-bit match mask.
    unsigned mask = 0;
    #pragma unroll
    for (int j = 0; j < 4; ++j) {
        uint4 kk = k4[k * 4 + j];
        int e = k * 16 + j * 4;
        mask |= (unsigned)((__popc(kk.x ^ ra) | ((e + 0 >= n) ? 64 : 0)) == dmin) << (j * 4 + 0);
        mask |= (unsigned)((__popc(kk.y ^ ra) | ((e + 1 >= n) ? 64 : 0)) == dmin) << (j * 4 + 1);
        mask |= (unsigned)((__popc(kk.z ^ ra) | ((e + 2 >= n) ? 64 : 0)) == dmin) << (j * 4 + 2);
        mask |= (unsigned)((__popc(kk.w ^ ra) | ((e + 3 >= n) ? 64 : 0)) == dmin) << (j * 4 + 3);
    }

    // Assemble full 128-entry match mask m[4] from the 8 lanes' 16-bit pieces.
    unsigned m0 = (unsigned)__shfl((int)mask, 0, 8) | ((unsigned)__shfl((int)mask, 1, 8) << 16);
    unsigned m1 = (unsigned)__shfl((int)mask, 2, 8) | ((unsigned)__shfl((int)mask, 3, 8) << 16);
    unsigned m2 = (unsigned)__shfl((int)mask, 4, 8) | ((unsigned)__shfl((int)mask, 5, 8) << 16);
    unsigned m3 = (unsigned)__shfl((int)mask, 6, 8) | ((unsigned)__shfl((int)mask, 7, 8) << 16);

    __syncthreads();   // valT now visible to all threads

    const int nm = __popc(m0) + __popc(m1) + __popc(m2) + __popc(m3);
    const float fn = (float)nm, inv = 1.0f / fn;
    const uint4* vT = (const uint4*)s_valT;
    float o[4];
    #pragma unroll
    for (int jj = 0; jj < 4; ++jj) {
        uint4 vt = vT[4 * k + jj];   // valT row for bit j = 4k+jj (b128 read)
        int ones = __popc(m0 & vt.x) + __popc(m1 & vt.y) + __popc(m2 & vt.z) + __popc(m3 & vt.w);
        o[jj] = (2.0f * (float)ones - fn) * inv;
    }
    float4* op = (float4*)(out + (((size_t)b * R_DIM + (size_t)rblk * RPB + rl) * VBITS + k * 4));
    *op = make_float4(o[0], o[1], o[2], o[3]);
}

extern "C" void kernel_launch(void* const* d_in, const int* in_sizes, int n_in,
                              void* d_out, int out_size, void* d_ws, size_t ws_size,
                              hipStream_t stream) {
    const float* waddr = (const float*)d_in[0]; // [16,128,20]
    const float* wval  = (const float*)d_in[1]; // [16,128,32]
    const float* raddr = (const float*)d_in[2]; // [16,2048,20]
    float* out = (float*)d_out;                 // [16,2048,32]

    fused_kernel<<<B_DIM * BLOCKS_PER_B, 256, 0, stream>>>(waddr, wval, raddr, out);
}